// Round 28
// baseline (47.169 us; speedup 1.0000x reference)
//
#include <hip/hip_runtime.h>

#define IND 256
#define KC  16   // k per chunk; 16 chunks; dbuf = 2*16*256*4 = 32 KB

typedef float v2f __attribute__((ext_vector_type(2)));   // nt-store needs native vec

__global__ __launch_bounds__(256, 4)
void FeatureEncodingLayer_30374008718005_kernel(
        const float* __restrict__ X,      // [1024][256]
        const float* __restrict__ W,      // [4096][256]
        const float* __restrict__ bias,   // [4096]
        float* __restrict__ outf)         // [1024][4][4][2048] float32 = Re(kron)
{
    // k-major W tile [k][unit], 256 units wide. Compute read: lane reads words
    // 4L..4L+3 -> each 8-lane group covers all 32 banks exactly once ->
    // conflict-free with NO swizzle. Staging: transpose-write, banks 2-way.
    __shared__ float Ws[2][KC][256];   // 32 KB -> 4 blocks/CU, 16 waves/CU

    const int tid  = threadIdx.x;
    const int lane = tid & 63;
    const int wid  = __builtin_amdgcn_readfirstlane(tid >> 6);  // wave 0..3

    // XCD-aware swizzle (bijective: 1024 = 8 XCD x 128).
    const int bid = ((int)blockIdx.x & 7) * 128 + ((int)blockIdx.x >> 3);

    const int ut = bid & 15;           // 16 unit tiles x 256 units (128 pairs)
    const int bt = bid >> 4;           // 64 batch tiles x 16 batches
    const int b0 = bt * 16;
    const int u0 = ut * 256;
    const int p0 = ut * 128;           // WIDE pair tile: 512B-contig wave stores

    const int ku = tid & 3;            // k-quad: local k = 4ku..4ku+3
    const int su = tid >> 2;           // unit subgroup 0..63

    const float* xc = X + (size_t)(b0 + 4 * wid) * IND;  // wave's 4 batches -> s_load

    float acc[4][4];                   // [batch][unit]
#pragma unroll
    for (int i = 0; i < 4; ++i)
#pragma unroll
        for (int j = 0; j < 4; ++j) acc[i][j] = 0.f;

    float4 pf[4];
#define STAGE_LOAD(c) do {                                                     \
    _Pragma("unroll")                                                          \
    for (int j = 0; j < 4; ++j)                                                \
        pf[j] = *reinterpret_cast<const float4*>(                              \
            W + (size_t)(u0 + su + 64 * j) * IND + (c) * KC + ku * 4);         \
    } while (0)

#define STAGE_WRITE(buf) do {                                                  \
    _Pragma("unroll")                                                          \
    for (int j = 0; j < 4; ++j) {                                              \
        const int u = su + 64 * j;                                             \
        Ws[buf][4 * ku + 0][u] = pf[j].x;                                      \
        Ws[buf][4 * ku + 1][u] = pf[j].y;                                      \
        Ws[buf][4 * ku + 2][u] = pf[j].z;                                      \
        Ws[buf][4 * ku + 3][u] = pf[j].w;                                      \
    }                                                                          \
    } while (0)

    // LDS-only barrier: global (nt) stores stay in flight across it.
#define LDS_BARRIER() do {                                                     \
    asm volatile("s_waitcnt lgkmcnt(0)" ::: "memory");                         \
    __builtin_amdgcn_s_barrier();                                              \
    } while (0)

    STAGE_LOAD(0);
    STAGE_WRITE(0);
    LDS_BARRIER();

    for (int c = 0; c < IND / KC; ++c) {
        const int cur = c & 1;
        if (c < IND / KC - 1) STAGE_LOAD(c + 1);   // prefetch (no wait yet)

        // compute: per k, 1 conflict-free ds_read_b128 (4 units) + 16 FMA
#pragma unroll
        for (int k = 0; k < KC; ++k) {
            const float4 wq = *reinterpret_cast<const float4*>(
                &Ws[cur][k][4 * lane]);            // units 4L..4L+3
            const int kg = c * KC + k;
#pragma unroll
            for (int i = 0; i < 4; ++i) {
                const float xv = xc[i * IND + kg]; // wave-uniform s_load
                acc[i][0] = fmaf(xv, wq.x, acc[i][0]);
                acc[i][1] = fmaf(xv, wq.y, acc[i][1]);
                acc[i][2] = fmaf(xv, wq.z, acc[i][2]);
                acc[i][3] = fmaf(xv, wq.w, acc[i][3]);
            }
        }
        if (c < IND / KC - 1) {
            STAGE_WRITE(cur ^ 1);                  // vmcnt wait: only its loads
            LDS_BARRIER();
        }
    }
#undef STAGE_LOAD
#undef STAGE_WRITE
#undef LDS_BARRIER

    // ---- epilogue: lane owns pairs 2L, 2L+1 (units 4L..4L+3); per (b, rc)
    // the wave stores 64 x float2 = 512B CONTIGUOUS (2x champion granularity).
    const float4 bv = *reinterpret_cast<const float4*>(bias + u0 + 4 * lane);

#pragma unroll
    for (int i = 0; i < 4; ++i) {
        const int b = b0 + 4 * wid + i;
        const float tA0 = acc[i][0] + bv.x;   // pair 2L:   units 4L, 4L+1
        const float tB0 = acc[i][1] + bv.y;
        const float tA1 = acc[i][2] + bv.z;   // pair 2L+1: units 4L+2, 4L+3
        const float tB1 = acc[i][3] + bv.w;
        float sA0, cA0, sB0, cB0, sA1, cA1, sB1, cB1;
        __sincosf(tA0, &sA0, &cA0);
        __sincosf(tB0, &sB0, &cB0);
        __sincosf(tA1, &sA1, &cA1);
        __sincosf(tB1, &sB1, &cB1);
        const float ca0 = 0.5f * (1.f + cA0), sa0 = 0.5f * (1.f - cA0);
        const float cb0 = 0.5f * (1.f + cB0), sb0 = 0.5f * (1.f - cB0);
        const float oo0 = 0.25f * sA0 * sB0;
        const float ca1 = 0.5f * (1.f + cA1), sa1 = 0.5f * (1.f - cA1);
        const float cb1 = 0.5f * (1.f + cB1), sb1 = 0.5f * (1.f - cB1);
        const float oo1 = 0.25f * sA1 * sB1;

        float* bp = outf + (size_t)b * 32768 + p0 + 2 * lane;
        const v2f zz = {0.f, 0.f};
#define NT2(rc, a, bb) do { v2f v_ = {(a), (bb)};                              \
        __builtin_nontemporal_store(v_, reinterpret_cast<v2f*>(bp + (rc) * 2048)); } while (0)
        NT2( 0,  ca0 * cb0,  ca1 * cb1);
        __builtin_nontemporal_store(zz, reinterpret_cast<v2f*>(bp +  1 * 2048));
        __builtin_nontemporal_store(zz, reinterpret_cast<v2f*>(bp +  2 * 2048));
        NT2( 3, -oo0,       -oo1);
        __builtin_nontemporal_store(zz, reinterpret_cast<v2f*>(bp +  4 * 2048));
        NT2( 5,  ca0 * sb0,  ca1 * sb1);
        NT2( 6,  oo0,        oo1);
        __builtin_nontemporal_store(zz, reinterpret_cast<v2f*>(bp +  7 * 2048));
        __builtin_nontemporal_store(zz, reinterpret_cast<v2f*>(bp +  8 * 2048));
        NT2( 9,  oo0,        oo1);
        NT2(10,  sa0 * cb0,  sa1 * cb1);
        __builtin_nontemporal_store(zz, reinterpret_cast<v2f*>(bp + 11 * 2048));
        NT2(12, -oo0,       -oo1);
        __builtin_nontemporal_store(zz, reinterpret_cast<v2f*>(bp + 13 * 2048));
        __builtin_nontemporal_store(zz, reinterpret_cast<v2f*>(bp + 14 * 2048));
        NT2(15,  sa0 * sb0,  sa1 * sb1);
#undef NT2
    }
}

extern "C" void kernel_launch(void* const* d_in, const int* in_sizes, int n_in,
                              void* d_out, int out_size, void* d_ws, size_t ws_size,
                              hipStream_t stream) {
    const float* X  = (const float*)d_in[0];
    const float* W  = (const float*)d_in[1];
    const float* bv = (const float*)d_in[2];

    // 64 bt x 16 ut = 1024 blocks, 256 threads, 4 blocks/CU (champion shape);
    // only the pair-tile width changed: 64 -> 128 pairs = 512B store segments.
    FeatureEncodingLayer_30374008718005_kernel<<<dim3(1024), dim3(256), 0, stream>>>(
        X, W, bv, (float*)d_out);
}